// Round 1
// baseline (1036.655 us; speedup 1.0000x reference)
//
#include <hip/hip_runtime.h>

// CFConv fused kernel for MI355X (gfx950).
// B=4, N=4096, K=30 (edges), C=64, E=300.
// out[b,n,c] = sum_k x[b, E_idx[b,n,k], c] * gelu(gelu(ef[b,n,k,:]@W1+b1)@W2+b2)[c]
//
// R1 change vs previous best (934 us): occupancy. Previous: 256-thread blocks,
// 64 KB LDS -> 2 blocks/CU -> 8 waves/CU (25%), each block duplicating the
// 48 KB read-only W1/W2 tiles. Now: 512-thread blocks (8 waves) share ONE
// weight copy; LDS = 40(W1t) + 8(W2t) + 8x4(h tiles) = 80 KB -> 2 blocks/CU
// -> 16 waves/CU (4/SIMD). __launch_bounds__(512,4) caps VGPR at 128.
// Also: E_idx loads hoisted to group start (breaks idx->x serial chain).

typedef __bf16 bf16x8 __attribute__((ext_vector_type(8)));
typedef float f32x4 __attribute__((ext_vector_type(4)));

#define B_    4
#define N_    4096
#define K_    30      // edges per node
#define C_    64
#define E_    300
#define EPAD  320     // K-dim of GEMM1 padded to 5 chunks of 64

__device__ __forceinline__ float gelu_exact(float v) {
    // torch exact GELU: 0.5*x*(1+erf(x/sqrt(2)))
    return 0.5f * v * (1.0f + erff(v * 0.70710678118654752440f));
}

__global__ __launch_bounds__(512, 4) void cfconv_kernel(
    const float* __restrict__ x,      // [B,N,C]
    const float* __restrict__ ef,     // [B,N,K,E]
    const int*   __restrict__ eidx,   // [B,N,K]
    const float* __restrict__ W1,     // [E,C]
    const float* __restrict__ b1,     // [C]
    const float* __restrict__ W2,     // [C,C]
    const float* __restrict__ b2,     // [C]
    float*       __restrict__ out,    // [B,N,C]
    int nocts)                        // B*N/8
{
    // LDS: 80 KB total -> 2 blocks/CU (160 KB), 16 waves/CU.
    __shared__ __align__(16) __bf16 Bt[64 * EPAD];    // W1^T swizzled: 40 KB
    __shared__ __align__(16) __bf16 W2t[64 * 64];     // W2^T swizzled:  8 KB
    __shared__ __align__(16) __bf16 Hb[8 * 32 * 64];  // h tiles:       32 KB

    const int tid = threadIdx.x;
    const int w   = tid >> 6;   // wave 0..7 -> group within octet
    const int l   = tid & 63;   // lane
    const int m16 = l & 15;     // row/col within 16
    const int q   = l >> 4;     // lane quad 0..3

    // ---- Stage W1 -> Bt (transposed to [n][k], bf16, XOR-swizzled blocks) ----
    for (int e = tid; e < 64 * EPAD; e += 512) {
        int k = e >> 6, n = e & 63;
        float v = (k < E_) ? W1[k * 64 + n] : 0.0f;
        int lb = k >> 3;
        int pb = (lb & ~7) | ((lb & 7) ^ (n & 7));
        Bt[n * EPAD + pb * 8 + (k & 7)] = (__bf16)v;
    }
    // ---- Stage W2 -> W2t (transposed [n][k], swizzled) ----
    for (int e = tid; e < 64 * 64; e += 512) {
        int k = e >> 6, n = e & 63;
        int pb = (k >> 3) ^ (n & 7);
        W2t[n * 64 + pb * 8 + (k & 7)] = (__bf16)W2[k * 64 + n];
    }
    // Per-lane bias values for the 4 column tiles
    float b1v[4], b2v[4];
#pragma unroll
    for (int ct = 0; ct < 4; ++ct) {
        b1v[ct] = b1[ct * 16 + m16];
        b2v[ct] = b2[ct * 16 + m16];
    }
    __syncthreads();  // only barrier needed; weights are read-only afterwards

    __bf16* hw = &Hb[w * 32 * 64];  // wave-private h tile [32 rows][64 cols]

    for (int oct = blockIdx.x; oct < nocts; oct += gridDim.x) {
        const int gq = oct * 8 + w;                   // group id = b*N + n
        const float* efg = ef + (size_t)gq * (K_ * E_);

        // Hoisted edge-index loads (phase C inputs; independent of GEMMs).
        const int* ig = eidx + gq * K_;
        int idxv[8];
#pragma unroll
        for (int rt = 0; rt < 2; ++rt)
#pragma unroll
            for (int reg = 0; reg < 4; ++reg) {
                int r = rt * 16 + q * 4 + reg;
                idxv[rt * 4 + reg] = (r < K_) ? ig[r] : 0;
            }

        // ================= GEMM1: h_pre = ef @ W1 =================
        f32x4 acc1[2][4];
#pragma unroll
        for (int rt = 0; rt < 2; ++rt)
#pragma unroll
            for (int ct = 0; ct < 4; ++ct)
                acc1[rt][ct] = (f32x4){0.f, 0.f, 0.f, 0.f};

#pragma unroll
        for (int kc = 0; kc < 5; ++kc) {
            // A-fragments straight from global (lane m=l&15 row, k contiguous 8)
            bf16x8 af[2][2];
#pragma unroll
            for (int rt = 0; rt < 2; ++rt) {
                int r = rt * 16 + m16;
#pragma unroll
                for (int kh = 0; kh < 2; ++kh) {
                    int k0 = kc * 64 + kh * 32 + q * 8;
                    f32x4 v0 = (f32x4){0.f, 0.f, 0.f, 0.f};
                    f32x4 v1 = (f32x4){0.f, 0.f, 0.f, 0.f};
                    if (r < K_ && k0 < E_) {
                        const float* p = efg + r * E_ + k0;
                        v0 = *(const f32x4*)p;
                        if (k0 + 4 < E_) v1 = *(const f32x4*)(p + 4);
                    }
                    bf16x8 a;
                    a[0] = (__bf16)v0[0]; a[1] = (__bf16)v0[1];
                    a[2] = (__bf16)v0[2]; a[3] = (__bf16)v0[3];
                    a[4] = (__bf16)v1[0]; a[5] = (__bf16)v1[1];
                    a[6] = (__bf16)v1[2]; a[7] = (__bf16)v1[3];
                    af[rt][kh] = a;
                }
            }
            // B-fragments from swizzled LDS (lane n=l&15 col, k contiguous 8)
            bf16x8 bfr[4][2];
#pragma unroll
            for (int ct = 0; ct < 4; ++ct) {
                int n = ct * 16 + m16;
#pragma unroll
                for (int kh = 0; kh < 2; ++kh) {
                    int lb = kc * 8 + kh * 4 + q;
                    int pb = (lb & ~7) | ((lb & 7) ^ (n & 7));
                    bfr[ct][kh] = *(const bf16x8*)&Bt[n * EPAD + pb * 8];
                }
            }
#pragma unroll
            for (int kh = 0; kh < 2; ++kh)
#pragma unroll
                for (int rt = 0; rt < 2; ++rt)
#pragma unroll
                    for (int ct = 0; ct < 4; ++ct)
                        acc1[rt][ct] = __builtin_amdgcn_mfma_f32_16x16x32_bf16(
                            af[rt][kh], bfr[ct][kh], acc1[rt][ct], 0, 0, 0);
        }

        // ====== h = gelu(h_pre + b1) -> wave-private swizzled LDS ======
        // C-layout: row = rt*16 + q*4 + reg, col = ct*16 + m16
#pragma unroll
        for (int rt = 0; rt < 2; ++rt)
#pragma unroll
            for (int ct = 0; ct < 4; ++ct)
#pragma unroll
                for (int reg = 0; reg < 4; ++reg) {
                    int r = rt * 16 + q * 4 + reg;
                    int c = ct * 16 + m16;
                    float hv = gelu_exact(acc1[rt][ct][reg] + b1v[ct]);
                    hw[r * 64 + (((c >> 3) ^ (r & 7)) << 3) + (c & 7)] = (__bf16)hv;
                }

        // ================= GEMM2: w_pre = h @ W2 =================
        f32x4 acc2[2][4];
#pragma unroll
        for (int rt = 0; rt < 2; ++rt)
#pragma unroll
            for (int ct = 0; ct < 4; ++ct)
                acc2[rt][ct] = (f32x4){0.f, 0.f, 0.f, 0.f};

        bf16x8 ah[2][2];
#pragma unroll
        for (int rt = 0; rt < 2; ++rt) {
            int m = rt * 16 + m16;
#pragma unroll
            for (int kh = 0; kh < 2; ++kh) {
                int lb = kh * 4 + q;
                ah[rt][kh] = *(const bf16x8*)&hw[m * 64 + ((lb ^ (m & 7)) << 3)];
            }
        }
        bf16x8 bw[4][2];
#pragma unroll
        for (int ct = 0; ct < 4; ++ct) {
            int n = ct * 16 + m16;
#pragma unroll
            for (int kh = 0; kh < 2; ++kh) {
                int lb = kh * 4 + q;
                bw[ct][kh] = *(const bf16x8*)&W2t[n * 64 + ((lb ^ (n & 7)) << 3)];
            }
        }
#pragma unroll
        for (int kh = 0; kh < 2; ++kh)
#pragma unroll
            for (int rt = 0; rt < 2; ++rt)
#pragma unroll
                for (int ct = 0; ct < 4; ++ct)
                    acc2[rt][ct] = __builtin_amdgcn_mfma_f32_16x16x32_bf16(
                        ah[rt][kh], bw[ct][kh], acc2[rt][ct], 0, 0, 0);

        // ====== Phase C: W = gelu(w_pre + b2); out = sum_k x[idx[k]] * W[k] ======
        const int bb = gq >> 12;                       // / N_
        const float* xb = x + (size_t)bb * (N_ * C_);
        float s[4] = {0.f, 0.f, 0.f, 0.f};
#pragma unroll
        for (int rt = 0; rt < 2; ++rt)
#pragma unroll
            for (int reg = 0; reg < 4; ++reg) {
                int r = rt * 16 + q * 4 + reg;
                if (r < K_) {
                    const float* xr = xb + (size_t)idxv[rt * 4 + reg] * C_;
#pragma unroll
                    for (int ct = 0; ct < 4; ++ct) {
                        float wv = gelu_exact(acc2[rt][ct][reg] + b2v[ct]);
                        s[ct] = fmaf(wv, xr[ct * 16 + m16], s[ct]);
                    }
                }
            }
        // reduce across lane-quads (rows live in l>>4 dimension)
#pragma unroll
        for (int ct = 0; ct < 4; ++ct) {
            s[ct] += __shfl_xor(s[ct], 16, 64);
            s[ct] += __shfl_xor(s[ct], 32, 64);
        }
        // lane l writes column l of this group's output row
        float vout = (q == 0) ? s[0] : (q == 1) ? s[1] : (q == 2) ? s[2] : s[3];
        out[(size_t)gq * C_ + l] = vout;
    }
}

extern "C" void kernel_launch(void* const* d_in, const int* in_sizes, int n_in,
                              void* d_out, int out_size, void* d_ws, size_t ws_size,
                              hipStream_t stream) {
    const float* x   = (const float*)d_in[0];
    const float* ef  = (const float*)d_in[1];
    const int*   idx = (const int*)d_in[2];
    const float* W1  = (const float*)d_in[3];
    const float* b1  = (const float*)d_in[4];
    const float* W2  = (const float*)d_in[5];
    const float* b2  = (const float*)d_in[6];
    float* out = (float*)d_out;

    const int nocts = (B_ * N_) / 8;    // 2048
    dim3 grid(512), block(512);
    hipLaunchKernelGGL(cfconv_kernel, grid, block, 0, stream,
                       x, ef, idx, W1, b1, W2, b2, out, nocts);
}

// Round 2
// 1009.898 us; speedup vs baseline: 1.0265x; 1.0265x over previous
//
#include <hip/hip_runtime.h>

// CFConv fused kernel for MI355X (gfx950).
// B=4, N=4096, K=30 (edges), C=64, E=300.
// out[b,n,c] = sum_k x[b, E_idx[b,n,k], c] * gelu(gelu(ef[b,n,k,:]@W1+b1)@W2+b2)[c]
//
// R2: de-spill R1. R1's __launch_bounds__(512,4) (128 unified regs) spilled:
// VGPR_Count=64 (+64 AGPR for acc1+acc2), WRITE_SIZE 267 MB of scratch.
// Fixes while KEEPING 16 waves/CU (512 thr, 80 KB LDS, 2 blocks/CU):
//   - ONE acc[2][4] shared by both GEMMs (AGPR 64->32)
//   - B-fragments loaded per-ct (live 32->8 VGPRs), same LDS read count
//   - E_idx loads moved to GEMM2 (not live across GEMM1)
//   - wave-uniform bases via readfirstlane -> SGPR addressing

typedef __bf16 bf16x8 __attribute__((ext_vector_type(8)));
typedef float f32x4 __attribute__((ext_vector_type(4)));

#define B_    4
#define N_    4096
#define K_    30      // edges per node
#define C_    64
#define E_    300
#define EPAD  320     // K-dim of GEMM1 padded to 5 chunks of 64

__device__ __forceinline__ float gelu_exact(float v) {
    // torch exact GELU: 0.5*x*(1+erf(x/sqrt(2)))
    return 0.5f * v * (1.0f + erff(v * 0.70710678118654752440f));
}

__global__ __launch_bounds__(512, 4) void cfconv_kernel(
    const float* __restrict__ x,      // [B,N,C]
    const float* __restrict__ ef,     // [B,N,K,E]
    const int*   __restrict__ eidx,   // [B,N,K]
    const float* __restrict__ W1,     // [E,C]
    const float* __restrict__ b1,     // [C]
    const float* __restrict__ W2,     // [C,C]
    const float* __restrict__ b2,     // [C]
    float*       __restrict__ out,    // [B,N,C]
    int nocts)                        // B*N/8
{
    // LDS: 80 KB total -> 2 blocks/CU (160 KB), 16 waves/CU.
    __shared__ __align__(16) __bf16 Bt[64 * EPAD];    // W1^T swizzled: 40 KB
    __shared__ __align__(16) __bf16 W2t[64 * 64];     // W2^T swizzled:  8 KB
    __shared__ __align__(16) __bf16 Hb[8 * 32 * 64];  // h tiles:       32 KB

    const int tid = threadIdx.x;
    const int w   = __builtin_amdgcn_readfirstlane(tid >> 6);  // wave 0..7 (scalar)
    const int l   = tid & 63;   // lane
    const int m16 = l & 15;     // row/col within 16
    const int q   = l >> 4;     // lane quad 0..3

    // ---- Stage W1 -> Bt (transposed to [n][k], bf16, XOR-swizzled blocks) ----
    for (int e = tid; e < 64 * EPAD; e += 512) {
        int k = e >> 6, n = e & 63;
        float v = (k < E_) ? W1[k * 64 + n] : 0.0f;
        int lb = k >> 3;
        int pb = (lb & ~7) | ((lb & 7) ^ (n & 7));
        Bt[n * EPAD + pb * 8 + (k & 7)] = (__bf16)v;
    }
    // ---- Stage W2 -> W2t (transposed [n][k], swizzled) ----
    for (int e = tid; e < 64 * 64; e += 512) {
        int k = e >> 6, n = e & 63;
        int pb = (k >> 3) ^ (n & 7);
        W2t[n * 64 + pb * 8 + (k & 7)] = (__bf16)W2[k * 64 + n];
    }
    // Per-lane bias values for the 4 column tiles
    float b1v[4], b2v[4];
#pragma unroll
    for (int ct = 0; ct < 4; ++ct) {
        b1v[ct] = b1[ct * 16 + m16];
        b2v[ct] = b2[ct * 16 + m16];
    }
    __syncthreads();  // only barrier needed; weights are read-only afterwards

    __bf16* hw = &Hb[w * 32 * 64];  // wave-private h tile [32 rows][64 cols]

    for (int oct = blockIdx.x; oct < nocts; oct += gridDim.x) {
        const int gq = oct * 8 + w;                   // group id = b*N + n (uniform)
        const float* efg = ef + (size_t)gq * (K_ * E_);

        // Shared accumulator for BOTH GEMMs (keeps AGPR use at 32).
        f32x4 acc[2][4];
#pragma unroll
        for (int rt = 0; rt < 2; ++rt)
#pragma unroll
            for (int ct = 0; ct < 4; ++ct)
                acc[rt][ct] = (f32x4){0.f, 0.f, 0.f, 0.f};

        // ================= GEMM1: h_pre = ef @ W1 =================
#pragma unroll
        for (int kc = 0; kc < 5; ++kc) {
            // Issue all 8 raw global loads for this kc first (MLP), then convert.
            f32x4 raw[2][2][2];
#pragma unroll
            for (int rt = 0; rt < 2; ++rt) {
                int r = rt * 16 + m16;
                const float* pr = efg + r * E_;
#pragma unroll
                for (int kh = 0; kh < 2; ++kh) {
                    int k0 = kc * 64 + kh * 32 + q * 8;
                    bool ok = (r < K_) && (k0 < E_);
                    raw[rt][kh][0] = ok ? *(const f32x4*)(pr + k0)
                                        : (f32x4){0.f, 0.f, 0.f, 0.f};
                    raw[rt][kh][1] = (ok && (k0 + 4 < E_)) ? *(const f32x4*)(pr + k0 + 4)
                                                           : (f32x4){0.f, 0.f, 0.f, 0.f};
                }
            }
            bf16x8 af[2][2];
#pragma unroll
            for (int rt = 0; rt < 2; ++rt)
#pragma unroll
                for (int kh = 0; kh < 2; ++kh) {
                    bf16x8 a;
#pragma unroll
                    for (int j = 0; j < 4; ++j) {
                        a[j]     = (__bf16)raw[rt][kh][0][j];
                        a[4 + j] = (__bf16)raw[rt][kh][1][j];
                    }
                    af[rt][kh] = a;
                }
            // B-fragments loaded per-ct (only 2 live at a time -> 8 VGPRs)
#pragma unroll
            for (int ct = 0; ct < 4; ++ct) {
                int n = ct * 16 + m16;
                bf16x8 bfr0, bfr1;
                {
                    int lb = kc * 8 + q;
                    int pb = (lb & ~7) | ((lb & 7) ^ (n & 7));
                    bfr0 = *(const bf16x8*)&Bt[n * EPAD + pb * 8];
                }
                {
                    int lb = kc * 8 + 4 + q;
                    int pb = (lb & ~7) | ((lb & 7) ^ (n & 7));
                    bfr1 = *(const bf16x8*)&Bt[n * EPAD + pb * 8];
                }
#pragma unroll
                for (int rt = 0; rt < 2; ++rt) {
                    acc[rt][ct] = __builtin_amdgcn_mfma_f32_16x16x32_bf16(
                        af[rt][0], bfr0, acc[rt][ct], 0, 0, 0);
                    acc[rt][ct] = __builtin_amdgcn_mfma_f32_16x16x32_bf16(
                        af[rt][1], bfr1, acc[rt][ct], 0, 0, 0);
                }
            }
        }

        // ====== h = gelu(h_pre + b1) -> wave-private swizzled LDS ======
        // C-layout: row = rt*16 + q*4 + reg, col = ct*16 + m16
#pragma unroll
        for (int rt = 0; rt < 2; ++rt)
#pragma unroll
            for (int ct = 0; ct < 4; ++ct)
#pragma unroll
                for (int reg = 0; reg < 4; ++reg) {
                    int r = rt * 16 + q * 4 + reg;
                    int c = ct * 16 + m16;
                    float hv = gelu_exact(acc[rt][ct][reg] + b1v[ct]);
                    hw[r * 64 + (((c >> 3) ^ (r & 7)) << 3) + (c & 7)] = (__bf16)hv;
                }

        // ================= GEMM2: w_pre = h @ W2 =================
#pragma unroll
        for (int rt = 0; rt < 2; ++rt)
#pragma unroll
            for (int ct = 0; ct < 4; ++ct)
                acc[rt][ct] = (f32x4){0.f, 0.f, 0.f, 0.f};

        bf16x8 ah[2][2];
#pragma unroll
        for (int rt = 0; rt < 2; ++rt) {
            int m = rt * 16 + m16;
#pragma unroll
            for (int kh = 0; kh < 2; ++kh) {
                int lb = kh * 4 + q;
                ah[rt][kh] = *(const bf16x8*)&hw[m * 64 + ((lb ^ (m & 7)) << 3)];
            }
        }

        // Edge-index loads here: overlap GEMM2 MFMAs, not live during GEMM1.
        const int* ig = eidx + gq * K_;
        int idxv[8];
#pragma unroll
        for (int rt = 0; rt < 2; ++rt)
#pragma unroll
            for (int reg = 0; reg < 4; ++reg) {
                int r = rt * 16 + q * 4 + reg;
                idxv[rt * 4 + reg] = (r < K_) ? ig[r] : 0;
            }

#pragma unroll
        for (int ct = 0; ct < 4; ++ct) {
            int n = ct * 16 + m16;
            bf16x8 bw0, bw1;
            {
                int lb = q;
                bw0 = *(const bf16x8*)&W2t[n * 64 + ((lb ^ (n & 7)) << 3)];
            }
            {
                int lb = 4 + q;
                bw1 = *(const bf16x8*)&W2t[n * 64 + ((lb ^ (n & 7)) << 3)];
            }
#pragma unroll
            for (int rt = 0; rt < 2; ++rt) {
                acc[rt][ct] = __builtin_amdgcn_mfma_f32_16x16x32_bf16(
                    ah[rt][0], bw0, acc[rt][ct], 0, 0, 0);
                acc[rt][ct] = __builtin_amdgcn_mfma_f32_16x16x32_bf16(
                    ah[rt][1], bw1, acc[rt][ct], 0, 0, 0);
            }
        }

        // ====== Phase C: W = gelu(w_pre + b2); out = sum_k x[idx[k]] * W[k] ======
        const int bb = gq >> 12;                       // / N_
        const float* xb = x + (size_t)bb * (N_ * C_);
        float s[4] = {0.f, 0.f, 0.f, 0.f};
#pragma unroll
        for (int rt = 0; rt < 2; ++rt)
#pragma unroll
            for (int reg = 0; reg < 4; ++reg) {
                int r = rt * 16 + q * 4 + reg;
                if (r < K_) {
                    const float* xr = xb + (size_t)idxv[rt * 4 + reg] * C_;
#pragma unroll
                    for (int ct = 0; ct < 4; ++ct) {
                        float wv = gelu_exact(acc[rt][ct][reg] + b2v[ct]);
                        s[ct] = fmaf(wv, xr[ct * 16 + m16], s[ct]);
                    }
                }
            }
        // reduce across lane-quads (rows live in l>>4 dimension)
#pragma unroll
        for (int ct = 0; ct < 4; ++ct) {
            s[ct] += __shfl_xor(s[ct], 16, 64);
            s[ct] += __shfl_xor(s[ct], 32, 64);
        }
        // lane l writes column l of this group's output row
        float vout = (q == 0) ? s[0] : (q == 1) ? s[1] : (q == 2) ? s[2] : s[3];
        out[(size_t)gq * C_ + l] = vout;
    }
}

extern "C" void kernel_launch(void* const* d_in, const int* in_sizes, int n_in,
                              void* d_out, int out_size, void* d_ws, size_t ws_size,
                              hipStream_t stream) {
    const float* x   = (const float*)d_in[0];
    const float* ef  = (const float*)d_in[1];
    const int*   idx = (const int*)d_in[2];
    const float* W1  = (const float*)d_in[3];
    const float* b1  = (const float*)d_in[4];
    const float* W2  = (const float*)d_in[5];
    const float* b2  = (const float*)d_in[6];
    float* out = (float*)d_out;

    const int nocts = (B_ * N_) / 8;    // 2048
    dim3 grid(512), block(512);
    hipLaunchKernelGGL(cfconv_kernel, grid, block, 0, stream,
                       x, ef, idx, W1, b1, W2, b2, out, nocts);
}